// Round 1
// baseline (267.667 us; speedup 1.0000x reference)
//
#include <hip/hip_runtime.h>
#include <hip/hip_bf16.h>
#include <stdint.h>

typedef __attribute__((ext_vector_type(8))) short s16x8;
typedef __attribute__((ext_vector_type(4))) float f32x4;

#define MFMA16(a, b, c) __builtin_amdgcn_mfma_f32_16x16x32_bf16((a), (b), (c), 0, 0, 0)

__device__ __forceinline__ void gl_lds16(const void* g, void* l) {
  __builtin_amdgcn_global_load_lds(
      (__attribute__((address_space(1))) void*)(void*)g,
      (__attribute__((address_space(3))) void*)l,
      16, 0, 0);
}

__device__ __forceinline__ unsigned short f2bf(float f) {
  union { float f; uint32_t u; } c; c.f = f;
  return (unsigned short)((c.u + 0x7FFFu + ((c.u >> 16) & 1u)) >> 16);
}

__device__ __forceinline__ f32x4 max4(f32x4 a, f32x4 b) {
  f32x4 c;
  c[0] = fmaxf(a[0], b[0]); c[1] = fmaxf(a[1], b[1]);
  c[2] = fmaxf(a[2], b[2]); c[3] = fmaxf(a[3], b[3]);
  return c;
}

// ---------------- f32 -> bf16 convert (vectorized x4) ----------------
__global__ __launch_bounds__(256) void cvt4(const float* __restrict__ in,
                                            unsigned short* __restrict__ out, int n4) {
  int i = blockIdx.x * 256 + threadIdx.x;
  if (i >= n4) return;
  float4 v = ((const float4*)in)[i];
  ushort4 o;
  o.x = f2bf(v.x); o.y = f2bf(v.y); o.z = f2bf(v.z); o.w = f2bf(v.w);
  ((ushort4*)out)[i] = o;
}

// ---------------- conv1d over CLS tokens (f32) ----------------
// g[clip][ci][t] = x[(clip*8+t)*197*768 + ci]; y[clip,co,t] = b[co] + sum_{ci,dt} g[clip][ci][t+dt-1]*w[co][ci][dt]
// tcq/tck[b=clip*8+t][co] = y
__global__ __launch_bounds__(256) void conv_cls(
    const float* __restrict__ x,
    const float* __restrict__ wq, const float* __restrict__ bq,
    const float* __restrict__ wk, const float* __restrict__ bk,
    float* __restrict__ tcq, float* __restrict__ tck) {
  __shared__ float g[768][10];  // [ci][t+1], zero-padded both ends
  const int tid = threadIdx.x;
  const int clip = blockIdx.y;
  const int chunk = blockIdx.x;  // 0..23 -> 32 co each
  for (int i = tid; i < 768 * 8; i += 256) {
    int tt = i / 768, ci = i % 768;
    g[ci][tt + 1] = x[(size_t)(clip * 8 + tt) * 151296 + ci];
  }
  for (int i = tid; i < 768; i += 256) { g[i][0] = 0.f; g[i][9] = 0.f; }
  __syncthreads();
  const int co = chunk * 32 + (tid >> 3);
  const int t = tid & 7;
  float aq = 0.f, ak = 0.f;
  const float* wqp = wq + (size_t)co * 2304;
  const float* wkp = wk + (size_t)co * 2304;
  for (int ci = 0; ci < 768; ++ci) {
    float g0 = g[ci][t], g1 = g[ci][t + 1], g2 = g[ci][t + 2];
    aq += g0 * wqp[ci * 3 + 0] + g1 * wqp[ci * 3 + 1] + g2 * wqp[ci * 3 + 2];
    ak += g0 * wkp[ci * 3 + 0] + g1 * wkp[ci * 3 + 1] + g2 * wkp[ci * 3 + 2];
  }
  int b = clip * 8 + t;
  tcq[b * 768 + co] = aq + bq[co];
  tck[b * 768 + co] = ak + bk[co];
}

// ---------------- QKV GEMM (128x128 tile, bf16 MFMA) ----------------
// Y[M=12608][N=2304] = A @ Bw^T + bias ; scatter into q'(+tcq)/k'(+tck)/v as (B,H,N,Dh) bf16
__global__ __launch_bounds__(256) void qkv_gemm(
    const unsigned short* __restrict__ A,    // x_bf 12608x768
    const unsigned short* __restrict__ Bw,   // w_qkv_bf 2304x768
    const float* __restrict__ bias,          // 2304
    const float* __restrict__ tcq, const float* __restrict__ tck,  // 64x768 f32
    unsigned short* __restrict__ Qo, unsigned short* __restrict__ Ko,
    unsigned short* __restrict__ Vo) {
  __shared__ __align__(16) unsigned short As[128][32];
  __shared__ __align__(16) unsigned short Bs[128][32];
  const int tid = threadIdx.x;
  const int w = tid >> 6, lane = tid & 63;
  const int wm = w >> 1, wn = w & 1;
  const int r = lane & 15, gq = lane >> 4;
  const int m0 = blockIdx.y * 128, n0 = blockIdx.x * 128;
  const int lrow = lane >> 2;
  const int lcol = (lane & 3) * 8;

  f32x4 acc[4][4] = {};

  for (int k0 = 0; k0 < 768; k0 += 32) {
    __syncthreads();
#pragma unroll
    for (int j = 0; j < 2; ++j) {
      int rowA = (w * 2 + j) * 16 + lrow;
      gl_lds16(A + (size_t)(m0 + rowA) * 768 + k0 + lcol, (char*)As + (w * 2 + j) * 1024);
      gl_lds16(Bw + (size_t)(n0 + rowA) * 768 + k0 + lcol, (char*)Bs + (w * 2 + j) * 1024);
    }
    __syncthreads();
    s16x8 af[4], bfr[4];
#pragma unroll
    for (int m = 0; m < 4; ++m) af[m] = *(const s16x8*)&As[wm * 64 + m * 16 + r][gq * 8];
#pragma unroll
    for (int n = 0; n < 4; ++n) bfr[n] = *(const s16x8*)&Bs[wn * 64 + n * 16 + r][gq * 8];
#pragma unroll
    for (int m = 0; m < 4; ++m)
#pragma unroll
      for (int n = 0; n < 4; ++n) acc[m][n] = MFMA16(af[m], bfr[n], acc[m][n]);
  }

#pragma unroll
  for (int m = 0; m < 4; ++m) {
#pragma unroll
    for (int n = 0; n < 4; ++n) {
#pragma unroll
      for (int rr = 0; rr < 4; ++rr) {
        int M = m0 + wm * 64 + m * 16 + gq * 4 + rr;
        int N = n0 + wn * 64 + n * 16 + r;
        if (M < 12608) {
          float v = acc[m][n][rr] + bias[N];
          int sec = N / 768, c = N % 768;
          int b = M / 197, nn = M % 197;
          int h = c >> 6, d = c & 63;
          size_t dst = ((size_t)(b * 12 + h) * 197 + nn) * 64 + d;
          if (sec == 0)      Qo[dst] = f2bf(v + tcq[b * 768 + c]);
          else if (sec == 1) Ko[dst] = f2bf(v + tck[b * 768 + c]);
          else               Vo[dst] = f2bf(v);
        }
      }
    }
  }
}

// ---------------- fused attention, one block per (b,h) ----------------
__global__ __launch_bounds__(256) void attn(
    const unsigned short* __restrict__ Q, const unsigned short* __restrict__ K,
    const unsigned short* __restrict__ V, unsigned short* __restrict__ O /*12608x768*/) {
  __shared__ __align__(16) unsigned short Ks[208][72];
  __shared__ __align__(16) unsigned short VTs[64][232];
  __shared__ __align__(16) unsigned short Ps[4][16][40];
  const int tid = threadIdx.x;
  const int bh = blockIdx.x;
  const int b = bh / 12, h = bh % 12;
  const size_t base = (size_t)bh * 12608;  // 197*64

  for (int i = tid; i < 197 * 8; i += 256) {
    int kk = i >> 3, seg = (i & 7) * 8;
    *(s16x8*)&Ks[kk][seg] = *(const s16x8*)(K + base + kk * 64 + seg);
  }
  for (int i = tid; i < 197 * 16; i += 256) {
    int kk = i >> 4, ds = (i & 15) * 4;
    ushort4 vv = *(const ushort4*)(V + base + kk * 64 + ds);
    VTs[ds + 0][kk] = vv.x; VTs[ds + 1][kk] = vv.y;
    VTs[ds + 2][kk] = vv.z; VTs[ds + 3][kk] = vv.w;
  }
  for (int i = tid; i < 64 * 35; i += 256) {  // zero pad cols 197..231
    int d = i / 35, c = 197 + i % 35;
    VTs[d][c] = 0;
  }
  __syncthreads();

  const int w = tid >> 6, lane = tid & 63;
  const int r = lane & 15, g = lane >> 4;

  for (int qt = w; qt < 13; qt += 4) {
    const int q0 = qt * 16;
    int qrow = q0 + r; if (qrow > 196) qrow = 196;
    const s16x8* qp = (const s16x8*)(Q + base + (size_t)qrow * 64);
    s16x8 aq0 = qp[g];
    s16x8 aq1 = qp[4 + g];

    f32x4 s[13];
#pragma unroll
    for (int j = 0; j < 13; ++j) {
      f32x4 z = {};
      z = MFMA16(aq0, *(const s16x8*)&Ks[j * 16 + r][g * 8], z);
      z = MFMA16(aq1, *(const s16x8*)&Ks[j * 16 + r][32 + g * 8], z);
      s[j] = z;
    }
    if (r >= 5) { s[12][0] = -1e30f; s[12][1] = -1e30f; s[12][2] = -1e30f; s[12][3] = -1e30f; }

    f32x4 mx = s[0];
#pragma unroll
    for (int j = 1; j < 13; ++j) mx = max4(mx, s[j]);
#pragma unroll
    for (int off = 1; off < 16; off <<= 1) {
      f32x4 o_;
      o_[0] = __shfl_xor(mx[0], off, 64); o_[1] = __shfl_xor(mx[1], off, 64);
      o_[2] = __shfl_xor(mx[2], off, 64); o_[3] = __shfl_xor(mx[3], off, 64);
      mx = max4(mx, o_);
    }
    const float cexp = 0.125f * 1.44269504088896f;  // scale * log2(e)
    f32x4 sum = {};
#pragma unroll
    for (int j = 0; j < 13; ++j) {
      f32x4 p;
      p[0] = exp2f((s[j][0] - mx[0]) * cexp); p[1] = exp2f((s[j][1] - mx[1]) * cexp);
      p[2] = exp2f((s[j][2] - mx[2]) * cexp); p[3] = exp2f((s[j][3] - mx[3]) * cexp);
      s[j] = p;
      sum += p;
    }
#pragma unroll
    for (int off = 1; off < 16; off <<= 1) {
      sum[0] += __shfl_xor(sum[0], off, 64); sum[1] += __shfl_xor(sum[1], off, 64);
      sum[2] += __shfl_xor(sum[2], off, 64); sum[3] += __shfl_xor(sum[3], off, 64);
    }

    f32x4 o4[4] = {};
    for (int ks = 0; ks < 7; ++ks) {
      int j0 = ks * 2;
#pragma unroll
      for (int jj = 0; jj < 2; ++jj) {
        int jt = j0 + jj;
        int colb = jj * 16 + r;
        if (jt < 13) {
          f32x4 p = s[jt < 13 ? jt : 0];
          Ps[w][g * 4 + 0][colb] = f2bf(p[0]);
          Ps[w][g * 4 + 1][colb] = f2bf(p[1]);
          Ps[w][g * 4 + 2][colb] = f2bf(p[2]);
          Ps[w][g * 4 + 3][colb] = f2bf(p[3]);
        } else {
          Ps[w][g * 4 + 0][colb] = 0; Ps[w][g * 4 + 1][colb] = 0;
          Ps[w][g * 4 + 2][colb] = 0; Ps[w][g * 4 + 3][colb] = 0;
        }
      }
      asm volatile("s_waitcnt lgkmcnt(0)" ::: "memory");  // wave-local P transpose RAW
      s16x8 ap = *(const s16x8*)&Ps[w][r][g * 8];
#pragma unroll
      for (int n = 0; n < 4; ++n)
        o4[n] = MFMA16(ap, *(const s16x8*)&VTs[n * 16 + r][ks * 32 + g * 8], o4[n]);
    }

    f32x4 rinv;
    rinv[0] = 1.0f / sum[0]; rinv[1] = 1.0f / sum[1];
    rinv[2] = 1.0f / sum[2]; rinv[3] = 1.0f / sum[3];
#pragma unroll
    for (int n = 0; n < 4; ++n) {
#pragma unroll
      for (int rr = 0; rr < 4; ++rr) {
        int qr = q0 + g * 4 + rr;
        if (qr < 197)
          O[((size_t)(b * 197 + qr)) * 768 + h * 64 + n * 16 + r] = f2bf(o4[n][rr] * rinv[rr]);
      }
    }
  }
}

// ---------------- projection GEMM ----------------
__global__ __launch_bounds__(256) void proj_gemm(
    const unsigned short* __restrict__ A,   // attn out bf16 12608x768
    const unsigned short* __restrict__ Bw,  // w_proj bf16 768x768
    const float* __restrict__ bias,         // 768
    float* __restrict__ Out) {
  __shared__ __align__(16) unsigned short As[128][32];
  __shared__ __align__(16) unsigned short Bs[128][32];
  const int tid = threadIdx.x;
  const int w = tid >> 6, lane = tid & 63;
  const int wm = w >> 1, wn = w & 1;
  const int r = lane & 15, gq = lane >> 4;
  const int m0 = blockIdx.y * 128, n0 = blockIdx.x * 128;
  const int lrow = lane >> 2;
  const int lcol = (lane & 3) * 8;

  f32x4 acc[4][4] = {};

  for (int k0 = 0; k0 < 768; k0 += 32) {
    __syncthreads();
#pragma unroll
    for (int j = 0; j < 2; ++j) {
      int rowA = (w * 2 + j) * 16 + lrow;
      gl_lds16(A + (size_t)(m0 + rowA) * 768 + k0 + lcol, (char*)As + (w * 2 + j) * 1024);
      gl_lds16(Bw + (size_t)(n0 + rowA) * 768 + k0 + lcol, (char*)Bs + (w * 2 + j) * 1024);
    }
    __syncthreads();
    s16x8 af[4], bfr[4];
#pragma unroll
    for (int m = 0; m < 4; ++m) af[m] = *(const s16x8*)&As[wm * 64 + m * 16 + r][gq * 8];
#pragma unroll
    for (int n = 0; n < 4; ++n) bfr[n] = *(const s16x8*)&Bs[wn * 64 + n * 16 + r][gq * 8];
#pragma unroll
    for (int m = 0; m < 4; ++m)
#pragma unroll
      for (int n = 0; n < 4; ++n) acc[m][n] = MFMA16(af[m], bfr[n], acc[m][n]);
  }

#pragma unroll
  for (int m = 0; m < 4; ++m) {
#pragma unroll
    for (int n = 0; n < 4; ++n) {
#pragma unroll
      for (int rr = 0; rr < 4; ++rr) {
        int M = m0 + wm * 64 + m * 16 + gq * 4 + rr;
        int N = n0 + wn * 64 + n * 16 + r;
        if (M < 12608) Out[(size_t)M * 768 + N] = acc[m][n][rr] + bias[N];
      }
    }
  }
}

extern "C" void kernel_launch(void* const* d_in, const int* in_sizes, int n_in,
                              void* d_out, int out_size, void* d_ws, size_t ws_size,
                              hipStream_t stream) {
  const float* x       = (const float*)d_in[0];
  const float* w_qkv   = (const float*)d_in[1];
  const float* b_qkv   = (const float*)d_in[2];
  const float* w_proj  = (const float*)d_in[3];
  const float* b_proj  = (const float*)d_in[4];
  const float* conv_qw = (const float*)d_in[5];
  const float* conv_qb = (const float*)d_in[6];
  const float* conv_kw = (const float*)d_in[7];
  const float* conv_kb = (const float*)d_in[8];
  float* out = (float*)d_out;

  char* ws = (char*)d_ws;
  size_t off = 0;
  auto alloc = [&](size_t n) {
    char* p = ws + off;
    off = (off + n + 255) & ~(size_t)255;
    return p;
  };
  // order matters: OOB tile reads from x_bf/ao_bf must land inside the workspace
  unsigned short* x_bf    = (unsigned short*)alloc(12608ull * 768 * 2);
  unsigned short* ao_bf   = (unsigned short*)alloc(12608ull * 768 * 2);
  unsigned short* wqkv_bf = (unsigned short*)alloc(2304ull * 768 * 2);
  unsigned short* wproj_bf= (unsigned short*)alloc(768ull * 768 * 2);
  unsigned short* q_bf    = (unsigned short*)alloc(12608ull * 768 * 2);
  unsigned short* k_bf    = (unsigned short*)alloc(12608ull * 768 * 2);
  unsigned short* v_bf    = (unsigned short*)alloc(12608ull * 768 * 2);
  float* tcq = (float*)alloc(64 * 768 * 4);
  float* tck = (float*)alloc(64 * 768 * 4);
  if (off > ws_size) return;  // workspace too small; fail visibly

  cvt4<<<dim3((2420736 + 255) / 256), 256, 0, stream>>>(x, x_bf, 2420736);
  cvt4<<<dim3((442368 + 255) / 256), 256, 0, stream>>>(w_qkv, wqkv_bf, 442368);
  cvt4<<<dim3((147456 + 255) / 256), 256, 0, stream>>>(w_proj, wproj_bf, 147456);
  conv_cls<<<dim3(24, 8), 256, 0, stream>>>(x, conv_qw, conv_qb, conv_kw, conv_kb, tcq, tck);
  qkv_gemm<<<dim3(18, 99), 256, 0, stream>>>(x_bf, wqkv_bf, b_qkv, tcq, tck, q_bf, k_bf, v_bf);
  attn<<<dim3(768), 256, 0, stream>>>(q_bf, k_bf, v_bf, ao_bf);
  proj_gemm<<<dim3(6, 99), 256, 0, stream>>>(ao_bf, wproj_bf, b_proj, out);
}